// Round 1
// baseline (319.194 us; speedup 1.0000x reference)
//
#include <hip/hip_runtime.h>
#include <hip/hip_bf16.h>
#include <cstdint>
#include <cstddef>

#define NB 2
#define NH 8
#define BHN 16          // NB*NH
#define NN 3072         // tokens
#define CC 256          // channels
#define DD 32           // head dim
#define OUTW 3104       // NN + DD
#define VW 48           // padded v2p width (38 -> 48)
#define KP 384          // NH*VW, padded K for proj GEMM

typedef __attribute__((ext_vector_type(8))) __bf16 bf16x8;
typedef __attribute__((ext_vector_type(4))) short short4v;
typedef __attribute__((ext_vector_type(4))) float f32x4;

static __device__ __forceinline__ unsigned short f2bf(float f) {
    union { float f; unsigned u; } v; v.f = f;
    unsigned r = v.u + 0x7FFFu + ((v.u >> 16) & 1u);   // RNE
    return (unsigned short)(r >> 16);
}

static __device__ __forceinline__ bf16x8 ldb8(const unsigned short* p) {
    return *(const bf16x8*)p;
}

static __device__ __forceinline__ f32x4 mfma16(bf16x8 a, bf16x8 b, f32x4 c) {
    return __builtin_amdgcn_mfma_f32_16x16x32_bf16(a, b, c, 0, 0, 0);
}

// ---------------------------------------------------------------------------
// prep: bf16 casts of x1/x2, transposed weight panels, positional rows of v2pT
// ---------------------------------------------------------------------------
__global__ __launch_bounds__(256) void prep_kernel(
    const float* __restrict__ x1, const float* __restrict__ x2,
    const float* __restrict__ Wq, const float* __restrict__ Wkv,
    const float* __restrict__ Wpf,
    unsigned short* __restrict__ x1b, unsigned short* __restrict__ x2b,
    unsigned short* __restrict__ Wt, unsigned short* __restrict__ Wpft,
    unsigned short* __restrict__ v2pT)
{
    int i = blockIdx.x * 256 + threadIdx.x;
    const int S_X = NB * NN * CC;                 // 1572864
    if (i < S_X) { x1b[i] = f2bf(x1[i]); return; }
    i -= S_X;
    if (i < S_X) { x2b[i] = f2bf(x2[i]); return; }
    i -= S_X;
    const int S_WT = 768 * CC;                    // Wt[j][kk] = W^T
    if (i < S_WT) {
        int j = i >> 8, kk = i & 255;
        float w = (j < 256) ? Wq[kk * 256 + j] : Wkv[kk * 512 + (j - 256)];
        Wt[i] = f2bf(w);
        return;
    }
    i -= S_WT;
    const int S_WP = 256 * KP;                    // Wpft[c2][h*48+cc]
    if (i < S_WP) {
        int c2 = i / KP, t = i - c2 * KP;
        int h = t / VW, cc = t - h * VW;
        unsigned short v = 0;
        if (cc < 38) v = f2bf(Wpf[(h * 38 + cc) * 256 + c2]);
        Wpft[i] = v;
        return;
    }
    i -= S_WP;
    const int S_POS = BHN * 16 * NN;              // v2pT rows 32..47 (pos + zero pad)
    if (i < S_POS) {
        int n = i % NN;
        int r = i / NN;
        int bh = r >> 4;
        int c = (r & 15) + 32;
        float val = 0.f;
        if (c < 38) {
            float p3 = -1.f + 2.f * (float)(n % 48) / 47.f;   // ys[n%48]
            float p4 = -1.f + 2.f * (float)(n / 48) / 63.f;   // xs[n/48]
            float pv[6] = { p3 * p3, p4 * p4, p3 * p4, p3, p4, 1.f };
            val = pv[c - 32];
        }
        v2pT[((size_t)bh * VW + c) * NN + n] = f2bf(val);
    }
}

// ---------------------------------------------------------------------------
// qkv: [6144,256] x Wt^T -> q,k row-major [bh][n][32]; v scattered to v2pT
// cols 0..255 from x1 (Wq), 256..767 from x2 (Wkv)
// ---------------------------------------------------------------------------
__global__ __launch_bounds__(256) void qkv_kernel(
    const unsigned short* __restrict__ x1b, const unsigned short* __restrict__ x2b,
    const unsigned short* __restrict__ Wt,
    unsigned short* __restrict__ qbh, unsigned short* __restrict__ kbh,
    unsigned short* __restrict__ v2pT)
{
    int rt = blockIdx.x, ct = blockIdx.y;
    int wv = threadIdx.x >> 6, lane = threadIdx.x & 63;
    int g = lane >> 4, q = lane & 15;
    int row0 = rt * 64 + wv * 16;
    const unsigned short* A = (ct < 4) ? x1b : x2b;
    const unsigned short* arow = A + (size_t)(row0 + q) * CC + g * 8;
    const unsigned short* brow = Wt + (size_t)(ct * 64 + q) * CC + g * 8;
    f32x4 acc[4];
    #pragma unroll
    for (int cb = 0; cb < 4; ++cb) acc[cb] = f32x4{0.f, 0.f, 0.f, 0.f};
    for (int k0 = 0; k0 < CC; k0 += 32) {
        bf16x8 af = ldb8(arow + k0);
        #pragma unroll
        for (int cb = 0; cb < 4; ++cb)
            acc[cb] = mfma16(af, ldb8(brow + (size_t)cb * 16 * CC + k0), acc[cb]);
    }
    int b = row0 / NN, nb = row0 % NN;
    #pragma unroll
    for (int cb = 0; cb < 4; ++cb) {
        int jj = ct * 64 + cb * 16 + q;
        #pragma unroll
        for (int r = 0; r < 4; ++r) {
            int n = nb + 4 * g + r;
            unsigned short bv = f2bf(acc[cb][r]);
            if (jj < 256) {
                int h = jj >> 5, c = jj & 31;
                qbh[(size_t)((b * NH + h) * NN + n) * DD + c] = bv;
            } else if (jj < 512) {
                int jk = jj - 256; int h = jk >> 5, c = jk & 31;
                kbh[(size_t)((b * NH + h) * NN + n) * DD + c] = bv;
            } else {
                int jv = jj - 512; int h = jv >> 5, c = jv & 31;
                v2pT[(size_t)((b * NH + h) * VW + c) * NN + n] = bv;
            }
        }
    }
}

// ---------------------------------------------------------------------------
// fused attention: per (bh, 64-row q-tile); 4 independent waves x 16 q-rows.
// Pass A: l[q] = sum_m exp(s*scale)   (no max-sub: logits are ~N(0,0.1))
// Pass B: recompute S^T, write normalized attn (dwordx4, 64B-coalesced),
//         LDS-relayout p, accumulate y^T = v2pT * p^T, store yacc bf16.
// ---------------------------------------------------------------------------
__global__ __launch_bounds__(256) void attn_kernel(
    const unsigned short* __restrict__ qbh, const unsigned short* __restrict__ kbh,
    const unsigned short* __restrict__ v2pT,
    float* __restrict__ out, unsigned short* __restrict__ yacc)
{
    __shared__ unsigned short plds[4][16][40];   // wave-private p tiles, stride 80B
    const float SCALE = 0.17677669529663687f;    // 1/sqrt(32)

    int bh = blockIdx.x;        // 0..15
    int qt = blockIdx.y;        // 0..47
    int wv = threadIdx.x >> 6, lane = threadIdx.x & 63;
    int g = lane >> 4, q = lane & 15;
    int qrow = qt * 64 + wv * 16;

    bf16x8 qf = ldb8(qbh + (size_t)(bh * NN + qrow + q) * DD + g * 8);
    const unsigned short* kbase = kbh + (size_t)bh * NN * DD;
    const unsigned short* vbase = v2pT + (size_t)bh * VW * NN;

    // ---- pass A: row sums of exp ----
    float l = 0.f;
    for (int m0 = 0; m0 < NN; m0 += 16) {
        bf16x8 kf = ldb8(kbase + (size_t)(m0 + q) * DD + g * 8);
        f32x4 z = {0.f, 0.f, 0.f, 0.f};
        f32x4 s = mfma16(kf, qf, z);
        #pragma unroll
        for (int r = 0; r < 4; ++r) l += __expf(s[r] * SCALE);
    }
    l += __shfl_xor(l, 16, 64);
    l += __shfl_xor(l, 32, 64);
    float invl = 1.f / l;

    // ---- pass B ----
    f32x4 yt0 = {0.f,0.f,0.f,0.f}, yt1 = yt0, yt2 = yt0;
    float* orow = out + (size_t)(bh * NN + qrow + q) * OUTW;
    unsigned short* pl = &plds[wv][q][0];

    for (int m0 = 0; m0 < NN; m0 += 32) {
        bf16x8 kf0 = ldb8(kbase + (size_t)(m0 + q) * DD + g * 8);
        bf16x8 kf1 = ldb8(kbase + (size_t)(m0 + 16 + q) * DD + g * 8);
        f32x4 z = {0.f, 0.f, 0.f, 0.f};
        f32x4 s0 = mfma16(kf0, qf, z);
        f32x4 s1 = mfma16(kf1, qf, z);
        f32x4 p0, p1;
        #pragma unroll
        for (int r = 0; r < 4; ++r) {
            p0[r] = __expf(s0[r] * SCALE) * invl;
            p1[r] = __expf(s1[r] * SCALE) * invl;
        }
        // coalesced attn store: lane holds 4 consecutive m of one q-row
        *(f32x4*)(orow + m0 + 4 * g) = p0;
        *(f32x4*)(orow + m0 + 16 + 4 * g) = p1;
        // re-layout p through wave-private LDS for the PV B-operand
        short4v pk0, pk1;
        #pragma unroll
        for (int r = 0; r < 4; ++r) {
            pk0[r] = (short)f2bf(p0[r]);
            pk1[r] = (short)f2bf(p1[r]);
        }
        *(short4v*)(pl + 4 * g) = pk0;
        *(short4v*)(pl + 16 + 4 * g) = pk1;
        asm volatile("s_waitcnt lgkmcnt(0)" ::: "memory");
        bf16x8 pf = ldb8(pl + 8 * g);
        bf16x8 vf0 = ldb8(vbase + (size_t)(q) * NN + m0 + g * 8);
        bf16x8 vf1 = ldb8(vbase + (size_t)(16 + q) * NN + m0 + g * 8);
        bf16x8 vf2 = ldb8(vbase + (size_t)(32 + q) * NN + m0 + g * 8);
        yt0 = mfma16(vf0, pf, yt0);
        yt1 = mfma16(vf1, pf, yt1);
        yt2 = mfma16(vf2, pf, yt2);
    }

    // epilogue: y^T frag -> yacc[b*NN+n][h*48 + c] bf16
    int b = bh >> 3, h = bh & 7;
    int nrow = qrow + q;
    unsigned short* yrow = yacc + (size_t)(b * NN + nrow) * KP + h * VW;
    f32x4 yts[3] = { yt0, yt1, yt2 };
    #pragma unroll
    for (int cb = 0; cb < 3; ++cb) {
        short4v pk;
        #pragma unroll
        for (int r = 0; r < 4; ++r) pk[r] = (short)f2bf(yts[cb][r]);
        *(short4v*)(yrow + cb * 16 + 4 * g) = pk;
    }
}

// ---------------------------------------------------------------------------
// proj: yacc[6144][384]bf16 @ Wpft[256][384]bf16 + bpf -> out cols 3072..3103
// ---------------------------------------------------------------------------
__global__ __launch_bounds__(256) void proj_kernel(
    const unsigned short* __restrict__ yacc, const unsigned short* __restrict__ Wpft,
    const float* __restrict__ bpf, float* __restrict__ out)
{
    int rt = blockIdx.x, ct = blockIdx.y;
    int wv = threadIdx.x >> 6, lane = threadIdx.x & 63;
    int g = lane >> 4, q = lane & 15;
    int row0 = rt * 64 + wv * 16;
    const unsigned short* arow = yacc + (size_t)(row0 + q) * KP + g * 8;
    const unsigned short* b0 = Wpft + (size_t)(ct * 64 + q) * KP + g * 8;
    f32x4 acc[4];
    #pragma unroll
    for (int cb = 0; cb < 4; ++cb) acc[cb] = f32x4{0.f, 0.f, 0.f, 0.f};
    for (int k0 = 0; k0 < KP; k0 += 32) {
        bf16x8 af = ldb8(arow + k0);
        #pragma unroll
        for (int cb = 0; cb < 4; ++cb)
            acc[cb] = mfma16(af, ldb8(b0 + (size_t)cb * 16 * KP + k0), acc[cb]);
    }
    int b = row0 / NN, nb = row0 % NN;
    #pragma unroll
    for (int cb = 0; cb < 4; ++cb) {
        int c2 = ct * 64 + cb * 16 + q;
        float bias = bpf[c2];
        int h = c2 >> 5, c = c2 & 31;
        float* obase = out + (size_t)((b * NH + h) * NN) * OUTW + NN + c;
        #pragma unroll
        for (int r = 0; r < 4; ++r) {
            int n = nb + 4 * g + r;
            obase[(size_t)n * OUTW] = acc[cb][r] + bias;
        }
    }
}

// ---------------------------------------------------------------------------
extern "C" void kernel_launch(void* const* d_in, const int* in_sizes, int n_in,
                              void* d_out, int out_size, void* d_ws, size_t ws_size,
                              hipStream_t stream)
{
    (void)in_sizes; (void)n_in; (void)out_size; (void)ws_size;
    const float* x1  = (const float*)d_in[0];
    const float* x2  = (const float*)d_in[1];
    const float* Wq  = (const float*)d_in[2];
    const float* Wkv = (const float*)d_in[3];
    const float* Wpf = (const float*)d_in[4];
    const float* bpf = (const float*)d_in[5];
    float* out = (float*)d_out;
    char* ws = (char*)d_ws;

    unsigned short* x1b  = (unsigned short*)(ws + 0);          // 3,145,728 B
    unsigned short* x2b  = (unsigned short*)(ws + 3145728);    // 3,145,728 B
    unsigned short* Wt   = (unsigned short*)(ws + 6291456);    //   393,216 B
    unsigned short* Wpft = (unsigned short*)(ws + 6684672);    //   196,608 B
    unsigned short* qbh  = (unsigned short*)(ws + 6881280);    // 3,145,728 B
    unsigned short* kbh  = (unsigned short*)(ws + 10027008);   // 3,145,728 B
    unsigned short* v2pT = (unsigned short*)(ws + 13172736);   // 4,718,592 B
    unsigned short* yacc = (unsigned short*)(ws + 17891328);   // 4,718,592 B
    // total ws use: 22,609,920 B

    prep_kernel<<<16512, 256, 0, stream>>>(x1, x2, Wq, Wkv, Wpf, x1b, x2b, Wt, Wpft, v2pT);
    qkv_kernel<<<dim3(96, 12), 256, 0, stream>>>(x1b, x2b, Wt, qbh, kbh, v2pT);
    attn_kernel<<<dim3(16, 48), 256, 0, stream>>>(qbh, kbh, v2pT, out, yacc);
    proj_kernel<<<dim3(96, 4), 256, 0, stream>>>(yacc, Wpft, bpf, out);
}

// Round 2
// 256.357 us; speedup vs baseline: 1.2451x; 1.2451x over previous
//
#include <hip/hip_runtime.h>
#include <hip/hip_bf16.h>
#include <cstdint>
#include <cstddef>

#define NB 2
#define NH 8
#define BHN 16          // NB*NH
#define NN 3072         // tokens
#define CC 256          // channels
#define DD 32           // head dim
#define OUTW 3104       // NN + DD
#define VW 48           // padded v2p width (38 -> 48)
#define KP 384          // NH*VW, padded K for proj GEMM

typedef __attribute__((ext_vector_type(8))) __bf16 bf16x8;
typedef __attribute__((ext_vector_type(4))) short short4v;
typedef __attribute__((ext_vector_type(4))) float f32x4;

static __device__ __forceinline__ unsigned short f2bf(float f) {
    union { float f; unsigned u; } v; v.f = f;
    unsigned r = v.u + 0x7FFFu + ((v.u >> 16) & 1u);   // RNE
    return (unsigned short)(r >> 16);
}

static __device__ __forceinline__ bf16x8 ldb8(const unsigned short* p) {
    return *(const bf16x8*)p;
}

static __device__ __forceinline__ f32x4 mfma16(bf16x8 a, bf16x8 b, f32x4 c) {
    return __builtin_amdgcn_mfma_f32_16x16x32_bf16(a, b, c, 0, 0, 0);
}

// ---------------------------------------------------------------------------
// prep: bf16 casts of x1/x2, transposed weight panels, positional rows of v2pT
// ---------------------------------------------------------------------------
__global__ __launch_bounds__(256) void prep_kernel(
    const float* __restrict__ x1, const float* __restrict__ x2,
    const float* __restrict__ Wq, const float* __restrict__ Wkv,
    const float* __restrict__ Wpf,
    unsigned short* __restrict__ x1b, unsigned short* __restrict__ x2b,
    unsigned short* __restrict__ Wt, unsigned short* __restrict__ Wpft,
    unsigned short* __restrict__ v2pT)
{
    int i = blockIdx.x * 256 + threadIdx.x;
    const int S_X = NB * NN * CC;                 // 1572864
    if (i < S_X) { x1b[i] = f2bf(x1[i]); return; }
    i -= S_X;
    if (i < S_X) { x2b[i] = f2bf(x2[i]); return; }
    i -= S_X;
    const int S_WT = 768 * CC;                    // Wt[j][kk] = W^T
    if (i < S_WT) {
        int j = i >> 8, kk = i & 255;
        float w = (j < 256) ? Wq[kk * 256 + j] : Wkv[kk * 512 + (j - 256)];
        Wt[i] = f2bf(w);
        return;
    }
    i -= S_WT;
    const int S_WP = 256 * KP;                    // Wpft[c2][h*48+cc]
    if (i < S_WP) {
        int c2 = i / KP, t = i - c2 * KP;
        int h = t / VW, cc = t - h * VW;
        unsigned short v = 0;
        if (cc < 38) v = f2bf(Wpf[(h * 38 + cc) * 256 + c2]);
        Wpft[i] = v;
        return;
    }
    i -= S_WP;
    const int S_POS = BHN * 16 * NN;              // v2pT rows 32..47 (pos + zero pad)
    if (i < S_POS) {
        int n = i % NN;
        int r = i / NN;
        int bh = r >> 4;
        int c = (r & 15) + 32;
        float val = 0.f;
        if (c < 38) {
            float p3 = -1.f + 2.f * (float)(n % 48) / 47.f;   // ys[n%48]
            float p4 = -1.f + 2.f * (float)(n / 48) / 63.f;   // xs[n/48]
            float pv[6] = { p3 * p3, p4 * p4, p3 * p4, p3, p4, 1.f };
            val = pv[c - 32];
        }
        v2pT[((size_t)bh * VW + c) * NN + n] = f2bf(val);
    }
}

// ---------------------------------------------------------------------------
// qkv: [6144,256] x Wt^T -> q,k row-major [bh][n][32]; v scattered to v2pT
// ---------------------------------------------------------------------------
__global__ __launch_bounds__(256) void qkv_kernel(
    const unsigned short* __restrict__ x1b, const unsigned short* __restrict__ x2b,
    const unsigned short* __restrict__ Wt,
    unsigned short* __restrict__ qbh, unsigned short* __restrict__ kbh,
    unsigned short* __restrict__ v2pT)
{
    int rt = blockIdx.x, ct = blockIdx.y;
    int wv = threadIdx.x >> 6, lane = threadIdx.x & 63;
    int g = lane >> 4, q = lane & 15;
    int row0 = rt * 64 + wv * 16;
    const unsigned short* A = (ct < 4) ? x1b : x2b;
    const unsigned short* arow = A + (size_t)(row0 + q) * CC + g * 8;
    const unsigned short* brow = Wt + (size_t)(ct * 64 + q) * CC + g * 8;
    f32x4 acc[4];
    #pragma unroll
    for (int cb = 0; cb < 4; ++cb) acc[cb] = f32x4{0.f, 0.f, 0.f, 0.f};
    for (int k0 = 0; k0 < CC; k0 += 32) {
        bf16x8 af = ldb8(arow + k0);
        #pragma unroll
        for (int cb = 0; cb < 4; ++cb)
            acc[cb] = mfma16(af, ldb8(brow + (size_t)cb * 16 * CC + k0), acc[cb]);
    }
    int b = row0 / NN, nb = row0 % NN;
    #pragma unroll
    for (int cb = 0; cb < 4; ++cb) {
        int jj = ct * 64 + cb * 16 + q;
        #pragma unroll
        for (int r = 0; r < 4; ++r) {
            int n = nb + 4 * g + r;
            unsigned short bv = f2bf(acc[cb][r]);
            if (jj < 256) {
                int h = jj >> 5, c = jj & 31;
                qbh[(size_t)((b * NH + h) * NN + n) * DD + c] = bv;
            } else if (jj < 512) {
                int jk = jj - 256; int h = jk >> 5, c = jk & 31;
                kbh[(size_t)((b * NH + h) * NN + n) * DD + c] = bv;
            } else {
                int jv = jj - 512; int h = jv >> 5, c = jv & 31;
                v2pT[(size_t)((b * NH + h) * VW + c) * NN + n] = bv;
            }
        }
    }
}

// ---------------------------------------------------------------------------
// fused attention: per (bh, 64-row q-tile); 4 independent waves x 16 q-rows.
// Pass A: l[q] = sum_m exp(s*scale)   (no max-sub: logits are ~N(0,0.1))
// Pass B: recompute S^T, write normalized attn with NON-TEMPORAL dwordx4
//         stores (keep K/V L2-resident), LDS-relayout p, y^T = v2pT * p^T.
// ---------------------------------------------------------------------------
__global__ __launch_bounds__(256) void attn_kernel(
    const unsigned short* __restrict__ qbh, const unsigned short* __restrict__ kbh,
    const unsigned short* __restrict__ v2pT,
    float* __restrict__ out, unsigned short* __restrict__ yacc)
{
    __shared__ unsigned short plds[4][16][40];   // wave-private p tiles, stride 80B
    const float SCALE = 0.17677669529663687f;    // 1/sqrt(32)

    int bh = blockIdx.x;        // 0..15
    int qt = blockIdx.y;        // 0..47
    int wv = threadIdx.x >> 6, lane = threadIdx.x & 63;
    int g = lane >> 4, q = lane & 15;
    int qrow = qt * 64 + wv * 16;

    bf16x8 qf = ldb8(qbh + (size_t)(bh * NN + qrow + q) * DD + g * 8);
    const unsigned short* kbase = kbh + (size_t)bh * NN * DD;
    const unsigned short* vbase = v2pT + (size_t)bh * VW * NN;

    // ---- pass A: row sums of exp ----
    float l = 0.f;
    for (int m0 = 0; m0 < NN; m0 += 32) {
        bf16x8 kf0 = ldb8(kbase + (size_t)(m0 + q) * DD + g * 8);
        bf16x8 kf1 = ldb8(kbase + (size_t)(m0 + 16 + q) * DD + g * 8);
        f32x4 z = {0.f, 0.f, 0.f, 0.f};
        f32x4 s0 = mfma16(kf0, qf, z);
        f32x4 s1 = mfma16(kf1, qf, z);
        #pragma unroll
        for (int r = 0; r < 4; ++r)
            l += __expf(s0[r] * SCALE) + __expf(s1[r] * SCALE);
    }
    l += __shfl_xor(l, 16, 64);
    l += __shfl_xor(l, 32, 64);
    float invl = 1.f / l;

    // ---- pass B ----
    f32x4 yt0 = {0.f,0.f,0.f,0.f}, yt1 = yt0, yt2 = yt0;
    float* orow = out + (size_t)(bh * NN + qrow + q) * OUTW;
    unsigned short* pl = &plds[wv][q][0];

    for (int m0 = 0; m0 < NN; m0 += 32) {
        bf16x8 kf0 = ldb8(kbase + (size_t)(m0 + q) * DD + g * 8);
        bf16x8 kf1 = ldb8(kbase + (size_t)(m0 + 16 + q) * DD + g * 8);
        f32x4 z = {0.f, 0.f, 0.f, 0.f};
        f32x4 s0 = mfma16(kf0, qf, z);
        f32x4 s1 = mfma16(kf1, qf, z);
        f32x4 p0, p1;
        #pragma unroll
        for (int r = 0; r < 4; ++r) {
            p0[r] = __expf(s0[r] * SCALE) * invl;
            p1[r] = __expf(s1[r] * SCALE) * invl;
        }
        // non-temporal coalesced attn store (don't displace K/V in L2)
        __builtin_nontemporal_store(p0, (f32x4*)(orow + m0 + 4 * g));
        __builtin_nontemporal_store(p1, (f32x4*)(orow + m0 + 16 + 4 * g));
        // re-layout p through wave-private LDS for the PV B-operand
        short4v pk0, pk1;
        #pragma unroll
        for (int r = 0; r < 4; ++r) {
            pk0[r] = (short)f2bf(p0[r]);
            pk1[r] = (short)f2bf(p1[r]);
        }
        *(short4v*)(pl + 4 * g) = pk0;
        *(short4v*)(pl + 16 + 4 * g) = pk1;
        asm volatile("s_waitcnt lgkmcnt(0)" ::: "memory");
        __builtin_amdgcn_sched_barrier(0);
        bf16x8 pf = ldb8(pl + 8 * g);
        bf16x8 vf0 = ldb8(vbase + (size_t)(q) * NN + m0 + g * 8);
        bf16x8 vf1 = ldb8(vbase + (size_t)(16 + q) * NN + m0 + g * 8);
        bf16x8 vf2 = ldb8(vbase + (size_t)(32 + q) * NN + m0 + g * 8);
        yt0 = mfma16(vf0, pf, yt0);
        yt1 = mfma16(vf1, pf, yt1);
        yt2 = mfma16(vf2, pf, yt2);
    }

    // epilogue: y^T frag -> yacc[b*NN+n][h*48 + c] bf16
    int b = bh >> 3, h = bh & 7;
    int nrow = qrow + q;
    unsigned short* yrow = yacc + (size_t)(b * NN + nrow) * KP + h * VW;
    f32x4 yts[3] = { yt0, yt1, yt2 };
    #pragma unroll
    for (int cb = 0; cb < 3; ++cb) {
        short4v pk;
        #pragma unroll
        for (int r = 0; r < 4; ++r) pk[r] = (short)f2bf(yts[cb][r]);
        *(short4v*)(yrow + cb * 16 + 4 * g) = pk;
    }
}

// ---------------------------------------------------------------------------
// proj: yacc[6144][384]bf16 @ Wpft[256][384]bf16 + bpf -> out cols 3072..3103
// ---------------------------------------------------------------------------
__global__ __launch_bounds__(256) void proj_kernel(
    const unsigned short* __restrict__ yacc, const unsigned short* __restrict__ Wpft,
    const float* __restrict__ bpf, float* __restrict__ out)
{
    int rt = blockIdx.x, ct = blockIdx.y;
    int wv = threadIdx.x >> 6, lane = threadIdx.x & 63;
    int g = lane >> 4, q = lane & 15;
    int row0 = rt * 64 + wv * 16;
    const unsigned short* arow = yacc + (size_t)(row0 + q) * KP + g * 8;
    const unsigned short* b0 = Wpft + (size_t)(ct * 64 + q) * KP + g * 8;
    f32x4 acc[4];
    #pragma unroll
    for (int cb = 0; cb < 4; ++cb) acc[cb] = f32x4{0.f, 0.f, 0.f, 0.f};
    for (int k0 = 0; k0 < KP; k0 += 32) {
        bf16x8 af = ldb8(arow + k0);
        #pragma unroll
        for (int cb = 0; cb < 4; ++cb)
            acc[cb] = mfma16(af, ldb8(b0 + (size_t)cb * 16 * KP + k0), acc[cb]);
    }
    int b = row0 / NN, nb = row0 % NN;
    #pragma unroll
    for (int cb = 0; cb < 4; ++cb) {
        int c2 = ct * 64 + cb * 16 + q;
        float bias = bpf[c2];
        int h = c2 >> 5, c = c2 & 31;
        float* obase = out + (size_t)((b * NH + h) * NN) * OUTW + NN + c;
        #pragma unroll
        for (int r = 0; r < 4; ++r) {
            int n = nb + 4 * g + r;
            __builtin_nontemporal_store(acc[cb][r] + bias, &obase[(size_t)n * OUTW]);
        }
    }
}

// ---------------------------------------------------------------------------
extern "C" void kernel_launch(void* const* d_in, const int* in_sizes, int n_in,
                              void* d_out, int out_size, void* d_ws, size_t ws_size,
                              hipStream_t stream)
{
    (void)in_sizes; (void)n_in; (void)out_size; (void)ws_size;
    const float* x1  = (const float*)d_in[0];
    const float* x2  = (const float*)d_in[1];
    const float* Wq  = (const float*)d_in[2];
    const float* Wkv = (const float*)d_in[3];
    const float* Wpf = (const float*)d_in[4];
    const float* bpf = (const float*)d_in[5];
    float* out = (float*)d_out;
    char* ws = (char*)d_ws;

    unsigned short* x1b  = (unsigned short*)(ws + 0);          // 3,145,728 B
    unsigned short* x2b  = (unsigned short*)(ws + 3145728);    // 3,145,728 B
    unsigned short* Wt   = (unsigned short*)(ws + 6291456);    //   393,216 B
    unsigned short* Wpft = (unsigned short*)(ws + 6684672);    //   196,608 B
    unsigned short* qbh  = (unsigned short*)(ws + 6881280);    // 3,145,728 B
    unsigned short* kbh  = (unsigned short*)(ws + 10027008);   // 3,145,728 B
    unsigned short* v2pT = (unsigned short*)(ws + 13172736);   // 4,718,592 B
    unsigned short* yacc = (unsigned short*)(ws + 17891328);   // 4,718,592 B

    prep_kernel<<<16512, 256, 0, stream>>>(x1, x2, Wq, Wkv, Wpf, x1b, x2b, Wt, Wpft, v2pT);
    qkv_kernel<<<dim3(96, 12), 256, 0, stream>>>(x1b, x2b, Wt, qbh, kbh, v2pT);
    attn_kernel<<<dim3(16, 48), 256, 0, stream>>>(qbh, kbh, v2pT, out, yacc);
    proj_kernel<<<dim3(96, 4), 256, 0, stream>>>(yacc, Wpft, bpf, out);
}

// Round 3
// 253.322 us; speedup vs baseline: 1.2600x; 1.0120x over previous
//
#include <hip/hip_runtime.h>
#include <hip/hip_bf16.h>
#include <cstdint>
#include <cstddef>

#define NB 2
#define NH 8
#define BHN 16          // NB*NH
#define NN 3072         // tokens
#define CC 256          // channels
#define DD 32           // head dim
#define OUTW 3104       // NN + DD
#define VW 48           // padded v2p width (38 -> 48)
#define KP 384          // NH*VW, padded K for proj GEMM

typedef __attribute__((ext_vector_type(8))) __bf16 bf16x8;
typedef __attribute__((ext_vector_type(4))) short short4v;
typedef __attribute__((ext_vector_type(4))) float f32x4;

static __device__ __forceinline__ unsigned short f2bf(float f) {
    __hip_bfloat16 h = __float2bfloat16(f);          // RNE, compiler-optimal cvt
    return *reinterpret_cast<unsigned short*>(&h);
}

static __device__ __forceinline__ bf16x8 ldb8(const unsigned short* p) {
    return *(const bf16x8*)p;
}

static __device__ __forceinline__ f32x4 mfma16(bf16x8 a, bf16x8 b, f32x4 c) {
    return __builtin_amdgcn_mfma_f32_16x16x32_bf16(a, b, c, 0, 0, 0);
}

// ---------------------------------------------------------------------------
// prep: bf16 casts of x1/x2, transposed weight panels, positional rows of v2pT
// ---------------------------------------------------------------------------
__global__ __launch_bounds__(256) void prep_kernel(
    const float* __restrict__ x1, const float* __restrict__ x2,
    const float* __restrict__ Wq, const float* __restrict__ Wkv,
    const float* __restrict__ Wpf,
    unsigned short* __restrict__ x1b, unsigned short* __restrict__ x2b,
    unsigned short* __restrict__ Wt, unsigned short* __restrict__ Wpft,
    unsigned short* __restrict__ v2pT)
{
    int i = blockIdx.x * 256 + threadIdx.x;
    const int S_X = NB * NN * CC;                 // 1572864
    if (i < S_X) { x1b[i] = f2bf(x1[i]); return; }
    i -= S_X;
    if (i < S_X) { x2b[i] = f2bf(x2[i]); return; }
    i -= S_X;
    const int S_WT = 768 * CC;                    // Wt[j][kk] = W^T
    if (i < S_WT) {
        int j = i >> 8, kk = i & 255;
        float w = (j < 256) ? Wq[kk * 256 + j] : Wkv[kk * 512 + (j - 256)];
        Wt[i] = f2bf(w);
        return;
    }
    i -= S_WT;
    const int S_WP = 256 * KP;                    // Wpft[c2][h*48+cc]
    if (i < S_WP) {
        int c2 = i / KP, t = i - c2 * KP;
        int h = t / VW, cc = t - h * VW;
        unsigned short v = 0;
        if (cc < 38) v = f2bf(Wpf[(h * 38 + cc) * 256 + c2]);
        Wpft[i] = v;
        return;
    }
    i -= S_WP;
    const int S_POS = BHN * 16 * NN;              // v2pT rows 32..47 (pos + zero pad)
    if (i < S_POS) {
        int n = i % NN;
        int r = i / NN;
        int bh = r >> 4;
        int c = (r & 15) + 32;
        float val = 0.f;
        if (c < 38) {
            float p3 = -1.f + 2.f * (float)(n % 48) / 47.f;   // ys[n%48]
            float p4 = -1.f + 2.f * (float)(n / 48) / 63.f;   // xs[n/48]
            float pv[6] = { p3 * p3, p4 * p4, p3 * p4, p3, p4, 1.f };
            val = pv[c - 32];
        }
        v2pT[((size_t)bh * VW + c) * NN + n] = f2bf(val);
    }
}

// ---------------------------------------------------------------------------
// qkv: [6144,256] x Wt^T -> q,k row-major [bh][n][32]; v scattered to v2pT
// ---------------------------------------------------------------------------
__global__ __launch_bounds__(256) void qkv_kernel(
    const unsigned short* __restrict__ x1b, const unsigned short* __restrict__ x2b,
    const unsigned short* __restrict__ Wt,
    unsigned short* __restrict__ qbh, unsigned short* __restrict__ kbh,
    unsigned short* __restrict__ v2pT)
{
    int rt = blockIdx.x, ct = blockIdx.y;
    int wv = threadIdx.x >> 6, lane = threadIdx.x & 63;
    int g = lane >> 4, q = lane & 15;
    int row0 = rt * 64 + wv * 16;
    const unsigned short* A = (ct < 4) ? x1b : x2b;
    const unsigned short* arow = A + (size_t)(row0 + q) * CC + g * 8;
    const unsigned short* brow = Wt + (size_t)(ct * 64 + q) * CC + g * 8;
    f32x4 acc[4];
    #pragma unroll
    for (int cb = 0; cb < 4; ++cb) acc[cb] = f32x4{0.f, 0.f, 0.f, 0.f};
    for (int k0 = 0; k0 < CC; k0 += 32) {
        bf16x8 af = ldb8(arow + k0);
        #pragma unroll
        for (int cb = 0; cb < 4; ++cb)
            acc[cb] = mfma16(af, ldb8(brow + (size_t)cb * 16 * CC + k0), acc[cb]);
    }
    int b = row0 / NN, nb = row0 % NN;
    #pragma unroll
    for (int cb = 0; cb < 4; ++cb) {
        int jj = ct * 64 + cb * 16 + q;
        #pragma unroll
        for (int r = 0; r < 4; ++r) {
            int n = nb + 4 * g + r;
            unsigned short bv = f2bf(acc[cb][r]);
            if (jj < 256) {
                int h = jj >> 5, c = jj & 31;
                qbh[(size_t)((b * NH + h) * NN + n) * DD + c] = bv;
            } else if (jj < 512) {
                int jk = jj - 256; int h = jk >> 5, c = jk & 31;
                kbh[(size_t)((b * NH + h) * NN + n) * DD + c] = bv;
            } else {
                int jv = jj - 512; int h = jv >> 5, c = jv & 31;
                v2pT[(size_t)((b * NH + h) * VW + c) * NN + n] = bv;
            }
        }
    }
}

// ---------------------------------------------------------------------------
// fused attention: block = (bh, 16-row q-tile); 4 waves split the m range
// into 768-wide quarters. Pass A: partial l via exp2(s*C), LDS-reduced.
// Pass B: recompute S^T, p = exp2(fma(s,C,-log2 l)), NT-store attn,
// LDS-relayout p, partial y^T; cross-wave y reduce in LDS at the end.
// Loads are issued BEFORE the NT stores each iteration so vmcnt waits for
// loads never drain the store stream (in-order vmcnt retirement).
// ---------------------------------------------------------------------------
__global__ __launch_bounds__(256, 4) void attn_kernel(
    const unsigned short* __restrict__ qbh, const unsigned short* __restrict__ kbh,
    const unsigned short* __restrict__ v2pT,
    float* __restrict__ out, unsigned short* __restrict__ yacc)
{
    __shared__ unsigned short plds[4][16][40];   // wave-private p tiles, stride 80B
    __shared__ float lsum[4][16];
    __shared__ float yl[4][48][17];
    const float C = 0.17677669529663687f * 1.4426950408889634f;  // scale*log2e

    int bh = blockIdx.x;        // 0..15
    int qt = blockIdx.y;        // 0..191
    int wv = threadIdx.x >> 6, lane = threadIdx.x & 63;
    int g = lane >> 4, q = lane & 15;
    int qrow = qt * 16;         // same 16 q-rows for all 4 waves
    int mbase = wv * 768;       // m-quarter per wave

    bf16x8 qf = ldb8(qbh + (size_t)(bh * NN + qrow + q) * DD + g * 8);
    const unsigned short* kbase = kbh + (size_t)bh * NN * DD;
    const unsigned short* vbase = v2pT + (size_t)bh * VW * NN;

    // ---- pass A: partial row sums of exp over this wave's m-quarter ----
    float l = 0.f;
    {
        bf16x8 kf0 = ldb8(kbase + (size_t)(mbase + q) * DD + g * 8);
        bf16x8 kf1 = ldb8(kbase + (size_t)(mbase + 16 + q) * DD + g * 8);
        for (int it = 0; it < 24; ++it) {
            int m0 = mbase + it * 32;
            // prefetch next-iter K (last iter reads ≤4KB past quarter: valid ws memory)
            bf16x8 kn0 = ldb8(kbase + (size_t)(m0 + 32 + q) * DD + g * 8);
            bf16x8 kn1 = ldb8(kbase + (size_t)(m0 + 48 + q) * DD + g * 8);
            f32x4 z = {0.f, 0.f, 0.f, 0.f};
            f32x4 s0 = mfma16(kf0, qf, z);
            f32x4 s1 = mfma16(kf1, qf, z);
            #pragma unroll
            for (int r = 0; r < 4; ++r)
                l += exp2f(s0[r] * C) + exp2f(s1[r] * C);
            kf0 = kn0; kf1 = kn1;
        }
    }
    l += __shfl_xor(l, 16, 64);
    l += __shfl_xor(l, 32, 64);
    if (lane < 16) lsum[wv][q] = l;
    __syncthreads();
    float ltot = lsum[0][q] + lsum[1][q] + lsum[2][q] + lsum[3][q];
    float nl2 = -__log2f(ltot);                  // p = exp2(s*C + nl2)

    // ---- pass B ----
    f32x4 yt0 = {0.f,0.f,0.f,0.f}, yt1 = yt0, yt2 = yt0;
    float* orow = out + (size_t)(bh * NN + qrow + q) * OUTW;
    unsigned short* pl = &plds[wv][q][0];

    bf16x8 kf0 = ldb8(kbase + (size_t)(mbase + q) * DD + g * 8);
    bf16x8 kf1 = ldb8(kbase + (size_t)(mbase + 16 + q) * DD + g * 8);
    for (int it = 0; it < 24; ++it) {
        int m0 = mbase + it * 32;
        // all loads first (before this iter's stores) so vmcnt waits on loads
        // never sit behind NT-store retirement
        bf16x8 kn0 = ldb8(kbase + (size_t)(m0 + 32 + q) * DD + g * 8);
        bf16x8 kn1 = ldb8(kbase + (size_t)(m0 + 48 + q) * DD + g * 8);
        bf16x8 vf0 = ldb8(vbase + (size_t)(q) * NN + m0 + g * 8);
        bf16x8 vf1 = ldb8(vbase + (size_t)(16 + q) * NN + m0 + g * 8);
        bf16x8 vf2 = ldb8(vbase + (size_t)(32 + q) * NN + m0 + g * 8);

        f32x4 z = {0.f, 0.f, 0.f, 0.f};
        f32x4 s0 = mfma16(kf0, qf, z);
        f32x4 s1 = mfma16(kf1, qf, z);
        f32x4 p0, p1;
        #pragma unroll
        for (int r = 0; r < 4; ++r) {
            p0[r] = exp2f(__builtin_fmaf(s0[r], C, nl2));
            p1[r] = exp2f(__builtin_fmaf(s1[r], C, nl2));
        }
        __builtin_nontemporal_store(p0, (f32x4*)(orow + m0 + 4 * g));
        __builtin_nontemporal_store(p1, (f32x4*)(orow + m0 + 16 + 4 * g));

        short4v pk0, pk1;
        #pragma unroll
        for (int r = 0; r < 4; ++r) {
            pk0[r] = (short)f2bf(p0[r]);
            pk1[r] = (short)f2bf(p1[r]);
        }
        *(short4v*)(pl + 4 * g) = pk0;
        *(short4v*)(pl + 16 + 4 * g) = pk1;
        asm volatile("s_waitcnt lgkmcnt(0)" ::: "memory");
        __builtin_amdgcn_sched_barrier(0);
        bf16x8 pf = ldb8(pl + 8 * g);
        yt0 = mfma16(vf0, pf, yt0);
        yt1 = mfma16(vf1, pf, yt1);
        yt2 = mfma16(vf2, pf, yt2);
        kf0 = kn0; kf1 = kn1;
    }

    // ---- cross-wave y^T reduce, then store yacc bf16 ----
    {
        f32x4 yts[3] = { yt0, yt1, yt2 };
        #pragma unroll
        for (int cb = 0; cb < 3; ++cb)
            #pragma unroll
            for (int r = 0; r < 4; ++r)
                yl[wv][cb * 16 + 4 * g + r][q] = yts[cb][r];
    }
    __syncthreads();
    if (wv < 3) {
        int cb = wv;
        int b = bh >> 3, h = bh & 7;
        unsigned short* yrow = yacc + (size_t)(b * NN + qrow + q) * KP + h * VW;
        short4v pk;
        #pragma unroll
        for (int r = 0; r < 4; ++r) {
            int c = cb * 16 + 4 * g + r;
            float s = yl[0][c][q] + yl[1][c][q] + yl[2][c][q] + yl[3][c][q];
            pk[r] = (short)f2bf(s);
        }
        *(short4v*)(yrow + cb * 16 + 4 * g) = pk;
    }
}

// ---------------------------------------------------------------------------
// proj: yacc[6144][384]bf16 @ Wpft[256][384]bf16 + bpf -> out cols 3072..3103
// ---------------------------------------------------------------------------
__global__ __launch_bounds__(256) void proj_kernel(
    const unsigned short* __restrict__ yacc, const unsigned short* __restrict__ Wpft,
    const float* __restrict__ bpf, float* __restrict__ out)
{
    int rt = blockIdx.x, ct = blockIdx.y;
    int wv = threadIdx.x >> 6, lane = threadIdx.x & 63;
    int g = lane >> 4, q = lane & 15;
    int row0 = rt * 64 + wv * 16;
    const unsigned short* arow = yacc + (size_t)(row0 + q) * KP + g * 8;
    const unsigned short* b0 = Wpft + (size_t)(ct * 64 + q) * KP + g * 8;
    f32x4 acc[4];
    #pragma unroll
    for (int cb = 0; cb < 4; ++cb) acc[cb] = f32x4{0.f, 0.f, 0.f, 0.f};
    for (int k0 = 0; k0 < KP; k0 += 32) {
        bf16x8 af = ldb8(arow + k0);
        #pragma unroll
        for (int cb = 0; cb < 4; ++cb)
            acc[cb] = mfma16(af, ldb8(b0 + (size_t)cb * 16 * KP + k0), acc[cb]);
    }
    int b = row0 / NN, nb = row0 % NN;
    #pragma unroll
    for (int cb = 0; cb < 4; ++cb) {
        int c2 = ct * 64 + cb * 16 + q;
        float bias = bpf[c2];
        int h = c2 >> 5, c = c2 & 31;
        float* obase = out + (size_t)((b * NH + h) * NN) * OUTW + NN + c;
        #pragma unroll
        for (int r = 0; r < 4; ++r) {
            int n = nb + 4 * g + r;
            __builtin_nontemporal_store(acc[cb][r] + bias, &obase[(size_t)n * OUTW]);
        }
    }
}

// ---------------------------------------------------------------------------
extern "C" void kernel_launch(void* const* d_in, const int* in_sizes, int n_in,
                              void* d_out, int out_size, void* d_ws, size_t ws_size,
                              hipStream_t stream)
{
    (void)in_sizes; (void)n_in; (void)out_size; (void)ws_size;
    const float* x1  = (const float*)d_in[0];
    const float* x2  = (const float*)d_in[1];
    const float* Wq  = (const float*)d_in[2];
    const float* Wkv = (const float*)d_in[3];
    const float* Wpf = (const float*)d_in[4];
    const float* bpf = (const float*)d_in[5];
    float* out = (float*)d_out;
    char* ws = (char*)d_ws;

    unsigned short* x1b  = (unsigned short*)(ws + 0);          // 3,145,728 B
    unsigned short* x2b  = (unsigned short*)(ws + 3145728);    // 3,145,728 B
    unsigned short* Wt   = (unsigned short*)(ws + 6291456);    //   393,216 B
    unsigned short* Wpft = (unsigned short*)(ws + 6684672);    //   196,608 B
    unsigned short* qbh  = (unsigned short*)(ws + 6881280);    // 3,145,728 B
    unsigned short* kbh  = (unsigned short*)(ws + 10027008);   // 3,145,728 B
    unsigned short* v2pT = (unsigned short*)(ws + 13172736);   // 4,718,592 B
    unsigned short* yacc = (unsigned short*)(ws + 17891328);   // 4,718,592 B

    prep_kernel<<<16512, 256, 0, stream>>>(x1, x2, Wq, Wkv, Wpf, x1b, x2b, Wt, Wpft, v2pT);
    qkv_kernel<<<dim3(96, 12), 256, 0, stream>>>(x1b, x2b, Wt, qbh, kbh, v2pT);
    attn_kernel<<<dim3(16, 192), 256, 0, stream>>>(qbh, kbh, v2pT, out, yacc);
    proj_kernel<<<dim3(96, 4), 256, 0, stream>>>(yacc, Wpft, bpf, out);
}